// Round 1
// baseline (61.634 us; speedup 1.0000x reference)
//
#include <hip/hip_runtime.h>

// PartitionPadding: ragged [N, D] rows (sorted segment ids) -> dense
// [B, max_atoms, D] zero-padded tensor. Output-centric gather so every
// output element is written every call (harness poisons d_out once).

#define BATCH 512

// Kernel 1: find segment starts from the sorted molecule_indicator.
// starts[m] = first index i with mol[i] == m; starts[B] = n.
// Every molecule has >= 1 atom, so every entry gets written.
__global__ void find_starts_kernel(const int* __restrict__ mol, int n,
                                   int* __restrict__ starts, int batch) {
    int i = blockIdx.x * blockDim.x + threadIdx.x;
    if (i >= n) return;
    if (i == 0) {
        starts[mol[0]] = 0;
        starts[batch] = n;
    } else if (mol[i] != mol[i - 1]) {
        starts[mol[i]] = i;
    }
}

// Kernel 2: output-centric gather/pad, vectorized float4 (16 B/lane).
// Block m = blockIdx.y owns molecule m. Thread covers output element
// j in [0, max_atoms*d4) float4s of that molecule's [max_atoms, D] slab:
//   a  = j >> log2(d4)   (within-molecule atom position)
//   dd = j &  (d4-1)     (feature float4 index)
// d4 = D/4 = 128 is a power of two -> pure shifts, no integer division.
__global__ void gather_pad_kernel(const float4* __restrict__ in,
                                  const int* __restrict__ starts,
                                  float4* __restrict__ out,
                                  int max_atoms, int row4) {
    const int m = blockIdx.y;
    const int s = starts[m];            // scalar (uniform) loads
    const int cnt = starts[m + 1] - s;
    const int j = blockIdx.x * blockDim.x + threadIdx.x;  // [0, max_atoms*128)
    if (j >= row4) return;
    const int a  = j >> 7;    // d4 == 128
    const int dd = j & 127;
    float4 v = make_float4(0.f, 0.f, 0.f, 0.f);
    if (a < cnt) {
        v = in[(long long)(s + a) * 128 + dd];
    }
    out[(long long)m * row4 + j] = v;
}

extern "C" void kernel_launch(void* const* d_in, const int* in_sizes, int n_in,
                              void* d_out, int out_size, void* d_ws, size_t ws_size,
                              hipStream_t stream) {
    const float* atom_features = (const float*)d_in[0];
    const int* mol = (const int*)d_in[1];
    float* out = (float*)d_out;

    const int n = in_sizes[1];                 // 65536 atoms
    const int d = in_sizes[0] / n;             // 512 features
    const int max_atoms = out_size / (BATCH * d);
    const int d4 = d / 4;                      // 128
    const int row4 = max_atoms * d4;           // float4s per molecule slab

    int* starts = (int*)d_ws;                  // BATCH+1 ints of scratch

    find_starts_kernel<<<(n + 255) / 256, 256, 0, stream>>>(mol, n, starts, BATCH);

    dim3 grid((row4 + 255) / 256, BATCH);
    gather_pad_kernel<<<grid, 256, 0, stream>>>(
        (const float4*)atom_features, starts, (float4*)out, max_atoms, row4);
}

// Round 3
// 54.261 us; speedup vs baseline: 1.1359x; 1.1359x over previous
//
#include <hip/hip_runtime.h>

// PartitionPadding: ragged [N, D] rows (sorted segment ids) -> dense
// [B, max_atoms, D] zero-padded tensor. Output-centric gather so every
// output element is written every call (harness poisons d_out once).

#define BATCH 512
#define UNROLL 8

typedef float f32x4 __attribute__((ext_vector_type(4)));  // native vec: ok for nontemporal builtins

// Kernel 1: find segment starts from the sorted molecule_indicator.
// starts[m] = first index i with mol[i] == m; starts[B] = n.
__global__ void find_starts_kernel(const int* __restrict__ mol, int n,
                                   int* __restrict__ starts, int batch) {
    int i = blockIdx.x * blockDim.x + threadIdx.x;
    if (i >= n) return;
    if (i == 0) {
        starts[mol[0]] = 0;
        starts[batch] = n;
    } else if (mol[i] != mol[i - 1]) {
        starts[mol[i]] = i;
    }
}

// Kernel 2: output-centric gather/pad, 16B vectors, 8 elements per thread.
// Key identity: flat within-slab float4 index j = a*128 + dd4, so the source
// address is in + s*128 + j (atoms of a molecule are contiguous). Only the
// pad predicate needs a = j>>7.
__global__ void gather_pad_kernel(const f32x4* __restrict__ in,
                                  const int* __restrict__ starts,
                                  f32x4* __restrict__ out,
                                  int row4) {
    const int m = blockIdx.y;
    const int s = starts[m];                 // uniform scalar loads
    const int cnt = starts[m + 1] - s;
    const f32x4* __restrict__ inm = in + (long long)s * 128;
    f32x4* __restrict__ outm = out + (long long)m * row4;

    int j = blockIdx.x * (blockDim.x * UNROLL) + threadIdx.x;
    #pragma unroll
    for (int u = 0; u < UNROLL; ++u, j += 256) {
        if (j < row4) {
            const int a = j >> 7;            // d4 == 128
            f32x4 v = (f32x4)(0.f);
            if (a < cnt) v = inm[j];
            __builtin_nontemporal_store(v, &outm[j]);
        }
    }
}

extern "C" void kernel_launch(void* const* d_in, const int* in_sizes, int n_in,
                              void* d_out, int out_size, void* d_ws, size_t ws_size,
                              hipStream_t stream) {
    const float* atom_features = (const float*)d_in[0];
    const int* mol = (const int*)d_in[1];
    float* out = (float*)d_out;

    const int n = in_sizes[1];                 // 65536 atoms
    const int d = in_sizes[0] / n;             // 512 features
    const int max_atoms = out_size / (BATCH * d);
    const int d4 = d / 4;                      // 128
    const int row4 = max_atoms * d4;           // float4s per molecule slab

    int* starts = (int*)d_ws;                  // BATCH+1 ints of scratch

    find_starts_kernel<<<(n + 255) / 256, 256, 0, stream>>>(mol, n, starts, BATCH);

    dim3 grid((row4 + 256 * UNROLL - 1) / (256 * UNROLL), BATCH);
    gather_pad_kernel<<<grid, 256, 0, stream>>>(
        (const f32x4*)atom_features, starts, (f32x4*)out, row4);
}